// Round 4
// baseline (7106.400 us; speedup 1.0000x reference)
//
#include <hip/hip_runtime.h>
#include <hip/hip_bf16.h>
#include <math.h>

#define B_   2
#define S_   2048
#define D_   2048
#define H_   16
#define HD_  128
#define ROT_ 32
#define M_   (B_*S_)    // 4096 tokens
#define N3_  (3*D_)     // 6144

static constexpr float SCALE_ = 0.08838834764831845f;  // 1/sqrt(128)

typedef __attribute__((ext_vector_type(4))) float  f32x4;
typedef __attribute__((ext_vector_type(8))) __bf16 bf16x8;

__device__ inline unsigned short f2bf(float f) {
    unsigned int u = __builtin_bit_cast(unsigned int, f);
    unsigned int r = (u + 0x7fffu + ((u >> 16) & 1u)) >> 16;
    return (unsigned short)r;
}
__device__ inline float bf2f(unsigned short h) {
    unsigned int u = ((unsigned int)h) << 16;
    return __builtin_bit_cast(float, u);
}

#define GLDS(g, l) __builtin_amdgcn_global_load_lds(                          \
    (const __attribute__((address_space(1))) void*)(g),                       \
    (__attribute__((address_space(3))) void*)(l), 16, 0, 0)

// ---------------------------------------------------------------- fused GEMM
// (identical to round 3)
// C = A @ B + bias.  A: M x K (fp32 if ABF16==0, bf16 if ABF16==1) row-major.
// B: K x N fp32 row-major (transposed+cast to bf16 in LDS during staging).
// MODE 0: write fp32 C (+bias) to out0. MODE 1: qkv epilogue (bias + RoPE +
// head-split scatter; partner of d<32 lives in acc[i][j^1][r] of same lane).
template <int ABF16, int MODE>
__global__ __launch_bounds__(256) void gemmf_kernel(
    const void* __restrict__ Aptr,
    const float* __restrict__ Bw,
    const float* __restrict__ bias,
    void* __restrict__ out0,
    unsigned short* __restrict__ out1,
    unsigned short* __restrict__ out2,
    int Ndim, int K)
{
    __shared__ unsigned short sA[128 * 32];
    __shared__ unsigned short sB[128 * 32];
    const int tid  = threadIdx.x;
    const int m0   = blockIdx.y * 128, n0 = blockIdx.x * 128;
    const int lane = tid & 63, wave = tid >> 6;
    const int wr = wave >> 1, wc = wave & 1;
    const int lrow = lane & 15, lk = (lane >> 4) * 8;

    f32x4 acc[4][4] = {};

    for (int k0 = 0; k0 < K; k0 += 32) {
        if (ABF16) {
            const unsigned short* Ab = (const unsigned short*)Aptr;
#pragma unroll
            for (int c = 0; c < 2; c++)
                GLDS(Ab + (size_t)(m0 + c*64 + tid/4) * K + k0 + (tid & 3) * 8,
                     sA + c*2048 + tid*8);
        } else {
            const float* Af = (const float*)Aptr;
#pragma unroll
            for (int p = 0; p < 4; p++) {
                int row = p*32 + tid/8, col = (tid & 7) * 4;
                float4 v = *(const float4*)&Af[(size_t)(m0 + row) * K + k0 + col];
                ushort4 o;
                o.x = f2bf(v.x); o.y = f2bf(v.y); o.z = f2bf(v.z); o.w = f2bf(v.w);
                *(ushort4*)&sA[row*32 + col] = o;
            }
        }
#pragma unroll
        for (int p = 0; p < 4; p++) {
            int krow = p*8 + tid/32, ncol = (tid & 31) * 4;
            float4 v = *(const float4*)&Bw[(size_t)(k0 + krow) * Ndim + n0 + ncol];
            sB[(ncol + 0)*32 + krow] = f2bf(v.x);
            sB[(ncol + 1)*32 + krow] = f2bf(v.y);
            sB[(ncol + 2)*32 + krow] = f2bf(v.z);
            sB[(ncol + 3)*32 + krow] = f2bf(v.w);
        }
        __syncthreads();
        bf16x8 af[4], bfj[4];
#pragma unroll
        for (int i = 0; i < 4; i++)
            af[i]  = *(const bf16x8*)&sA[(wr*64 + i*16 + lrow)*32 + lk];
#pragma unroll
        for (int j = 0; j < 4; j++)
            bfj[j] = *(const bf16x8*)&sB[(wc*64 + j*16 + lrow)*32 + lk];
#pragma unroll
        for (int i = 0; i < 4; i++)
#pragma unroll
            for (int j = 0; j < 4; j++)
                acc[i][j] = __builtin_amdgcn_mfma_f32_16x16x32_bf16(af[i], bfj[j], acc[i][j], 0, 0, 0);
        __syncthreads();
    }

    if (MODE == 0) {
#pragma unroll
        for (int i = 0; i < 4; i++) {
#pragma unroll
            for (int j = 0; j < 4; j++) {
                int col = n0 + wc*64 + j*16 + lrow;
                float bv = bias[col];
#pragma unroll
                for (int r = 0; r < 4; r++) {
                    int row = m0 + wr*64 + i*16 + (lane >> 4)*4 + r;
                    ((float*)out0)[(size_t)row * Ndim + col] = acc[i][j][r] + bv;
                }
            }
        }
    } else {
        const int t = n0 >> 7, part = t % 3, h = t / 3;
        float bv[4];
#pragma unroll
        for (int j = 0; j < 4; j++)
            bv[j] = bias[n0 + wc*64 + j*16 + lrow];

#pragma unroll
        for (int i = 0; i < 4; i++) {
            const int rowb = m0 + wr*64 + i*16 + (lane >> 4)*4;  // multiple of 4
            const int b = rowb >> 11, sbase = rowb & 2047;       // r=0..3 same b
            if (part == 2) {
                size_t vb = ((size_t)(b*H_ + h)) * HD_ * S_;
#pragma unroll
                for (int j = 0; j < 4; j++) {
                    int d = wc*64 + j*16 + lrow;
                    ushort4 o;
                    o.x = f2bf(acc[i][j][0] + bv[j]);
                    o.y = f2bf(acc[i][j][1] + bv[j]);
                    o.z = f2bf(acc[i][j][2] + bv[j]);
                    o.w = f2bf(acc[i][j][3] + bv[j]);
                    *(ushort4*)&out2[vb + (size_t)d * S_ + sbase] = o;
                }
            } else {
                unsigned short* outp = (part == 0) ? (unsigned short*)out0 : out1;
                size_t qb = ((size_t)(b*H_ + h)) * S_ * HD_;
#pragma unroll
                for (int r = 0; r < 4; r++) {
                    int s = sbase + r;
                    float vals[4];
#pragma unroll
                    for (int j = 0; j < 4; j++)
                        vals[j] = acc[i][j][r] + bv[j];
                    if (wc == 0) {
                        float inv = exp2f(-(float)lrow * 0.8304817737218413f); // 10000^(-lrow/16)
                        float ang = (float)s * inv, sn, cs;
                        sincosf(ang, &sn, &cs);
                        float v0 = vals[0]*cs - vals[1]*sn;   // d<16:  x*cos - x[d+16]*sin
                        float v1 = vals[1]*cs + vals[0]*sn;   // d>=16: x*cos + x[d-16]*sin
                        vals[0] = v0; vals[1] = v1;
                    }
#pragma unroll
                    for (int j = 0; j < 4; j++)
                        outp[qb + (size_t)s * HD_ + wc*64 + j*16 + lrow] = f2bf(vals[j]);
                }
            }
        }
    }
}

// ---------------------------------------------------------------- naive attention (bisect)
// One block per (q-row, bh). Two-pass softmax, fp32 scores in LDS.
// Q,K: [bh][s][d] bf16; Vt: [bh][d][s] bf16; ctx: [b][s][h*HD+d] bf16.
__global__ __launch_bounds__(256) void naive_attn_kernel(
    const unsigned short* __restrict__ Qg,
    const unsigned short* __restrict__ Kg,
    const unsigned short* __restrict__ Vt,
    unsigned short* __restrict__ ctx)
{
    __shared__ float qs[HD_];
    __shared__ float sc[S_];
    __shared__ float red[256];
    const int tid = threadIdx.x;
    const int q = blockIdx.x, bh = blockIdx.y;
    const int b = bh / H_, h = bh % H_;
    const unsigned short* Qb = Qg + ((size_t)bh * S_ + q) * HD_;
    const unsigned short* Kb = Kg + (size_t)bh * S_ * HD_;
    const unsigned short* Vb = Vt + (size_t)bh * HD_ * S_;

    if (tid < HD_) qs[tid] = bf2f(Qb[tid]);
    __syncthreads();

    const int nk = q + 1;
    float lmax = -1e30f;
    for (int k = tid; k < nk; k += 256) {
        const unsigned short* Kr = Kb + (size_t)k * HD_;
        float s = 0.f;
#pragma unroll
        for (int d4 = 0; d4 < HD_/4; d4++) {
            ushort4 kk = ((const ushort4*)Kr)[d4];
            s += qs[4*d4+0]*bf2f(kk.x) + qs[4*d4+1]*bf2f(kk.y)
               + qs[4*d4+2]*bf2f(kk.z) + qs[4*d4+3]*bf2f(kk.w);
        }
        s *= SCALE_;
        sc[k] = s;
        lmax = fmaxf(lmax, s);
    }
    red[tid] = lmax;
    __syncthreads();
    for (int off = 128; off > 0; off >>= 1) {
        if (tid < off) red[tid] = fmaxf(red[tid], red[tid + off]);
        __syncthreads();
    }
    float mx = red[0];
    __syncthreads();

    float lsum = 0.f;
    for (int k = tid; k < nk; k += 256) {
        float e = __expf(sc[k] - mx);
        sc[k] = e;
        lsum += e;
    }
    red[tid] = lsum;
    __syncthreads();
    for (int off = 128; off > 0; off >>= 1) {
        if (tid < off) red[tid] += red[tid + off];
        __syncthreads();
    }
    float denom = red[0];

    if (tid < HD_) {
        const unsigned short* Vr = Vb + (size_t)tid * S_;
        float o = 0.f;
        int k = 0;
        for (; k + 4 <= nk; k += 4) {
            ushort4 vv = *(const ushort4*)&Vr[k];
            o += sc[k+0]*bf2f(vv.x) + sc[k+1]*bf2f(vv.y)
               + sc[k+2]*bf2f(vv.z) + sc[k+3]*bf2f(vv.w);
        }
        for (; k < nk; k++) o += sc[k] * bf2f(Vr[k]);
        ctx[((size_t)b * S_ + q) * D_ + h*HD_ + tid] = f2bf(o / denom);
    }
}

// ---------------------------------------------------------------- launch
extern "C" void kernel_launch(void* const* d_in, const int* in_sizes, int n_in,
                              void* d_out, int out_size, void* d_ws, size_t ws_size,
                              hipStream_t stream) {
    const float* hs   = (const float*)d_in[0];
    // d_in[1] attention_mask: all ones, unused by the reference math
    const float* Wqkv = (const float*)d_in[2];
    const float* bqkv = (const float*)d_in[3];
    const float* Wd   = (const float*)d_in[4];
    const float* bd   = (const float*)d_in[5];
    float* out = (float*)d_out;

    char* ws  = (char*)d_ws;
    char* dob = (char*)d_out;
    // Memory map (identical to round 3; peak d_ws use: 32 MiB):
    //   ws[0,16MiB):   Vt  [bh][d][s] bf16
    //   ws[16,32MiB):  ctx [b][s][h*hd] bf16
    //   d_out[0,16MiB):  Qg [bh][s][d] bf16   (dead before gemm2 writes)
    //   d_out[16,32MiB): Kg [bh][s][d] bf16
    unsigned short* Vt  = (unsigned short*)(ws);
    unsigned short* ctx = (unsigned short*)(ws + 16777216);
    unsigned short* Qg  = (unsigned short*)(dob);
    unsigned short* Kg  = (unsigned short*)(dob + 16777216);

    // 1. fused QKV projection + bias + RoPE + head-split (+ V transpose)
    gemmf_kernel<0, 1><<<dim3(N3_/128, M_/128), dim3(256), 0, stream>>>(
        hs, Wqkv, bqkv, Qg, Kg, Vt, N3_, D_);
    // 2. causal attention — naive two-pass reference implementation (bisect)
    naive_attn_kernel<<<dim3(S_, B_*H_), dim3(256), 0, stream>>>(Qg, Kg, Vt, ctx);
    // 3. dense projection, fp32 out
    gemmf_kernel<1, 0><<<dim3(D_/128, M_/128), dim3(256), 0, stream>>>(
        ctx, Wd, bd, out, nullptr, nullptr, D_, D_);
}

// Round 5
// 1730.986 us; speedup vs baseline: 4.1054x; 4.1054x over previous
//
#include <hip/hip_runtime.h>
#include <hip/hip_bf16.h>
#include <math.h>

#define B_   2
#define S_   2048
#define D_   2048
#define H_   16
#define HD_  128
#define ROT_ 32
#define M_   (B_*S_)    // 4096 tokens
#define N3_  (3*D_)     // 6144

static constexpr float SCALE_ = 0.08838834764831845f;  // 1/sqrt(128)

typedef __attribute__((ext_vector_type(4))) float  f32x4;
typedef __attribute__((ext_vector_type(8))) __bf16 bf16x8;

__device__ inline unsigned short f2bf(float f) {
    unsigned int u = __builtin_bit_cast(unsigned int, f);
    unsigned int r = (u + 0x7fffu + ((u >> 16) & 1u)) >> 16;
    return (unsigned short)r;
}
__device__ inline float bf2f(unsigned short h) {
    unsigned int u = ((unsigned int)h) << 16;
    return __builtin_bit_cast(float, u);
}

#define GLDS(g, l) __builtin_amdgcn_global_load_lds(                          \
    (const __attribute__((address_space(1))) void*)(g),                       \
    (__attribute__((address_space(3))) void*)(l), 16, 0, 0)

// ---------------------------------------------------------------- fused GEMM
// (VERIFIED in round 4 — unchanged)
// C = A @ B + bias.  A: M x K (fp32 if ABF16==0, bf16 if ABF16==1) row-major.
// B: K x N fp32 row-major (transposed+cast to bf16 in LDS during staging).
// MODE 0: write fp32 C (+bias) to out0. MODE 1: qkv epilogue (bias + RoPE +
// head-split scatter; partner of d<32 lives in acc[i][j^1][r] of same lane).
template <int ABF16, int MODE>
__global__ __launch_bounds__(256) void gemmf_kernel(
    const void* __restrict__ Aptr,
    const float* __restrict__ Bw,
    const float* __restrict__ bias,
    void* __restrict__ out0,
    unsigned short* __restrict__ out1,
    unsigned short* __restrict__ out2,
    int Ndim, int K)
{
    __shared__ unsigned short sA[128 * 32];
    __shared__ unsigned short sB[128 * 32];
    const int tid  = threadIdx.x;
    const int m0   = blockIdx.y * 128, n0 = blockIdx.x * 128;
    const int lane = tid & 63, wave = tid >> 6;
    const int wr = wave >> 1, wc = wave & 1;
    const int lrow = lane & 15, lk = (lane >> 4) * 8;

    f32x4 acc[4][4] = {};

    for (int k0 = 0; k0 < K; k0 += 32) {
        if (ABF16) {
            const unsigned short* Ab = (const unsigned short*)Aptr;
#pragma unroll
            for (int c = 0; c < 2; c++)
                GLDS(Ab + (size_t)(m0 + c*64 + tid/4) * K + k0 + (tid & 3) * 8,
                     sA + c*2048 + tid*8);
        } else {
            const float* Af = (const float*)Aptr;
#pragma unroll
            for (int p = 0; p < 4; p++) {
                int row = p*32 + tid/8, col = (tid & 7) * 4;
                float4 v = *(const float4*)&Af[(size_t)(m0 + row) * K + k0 + col];
                ushort4 o;
                o.x = f2bf(v.x); o.y = f2bf(v.y); o.z = f2bf(v.z); o.w = f2bf(v.w);
                *(ushort4*)&sA[row*32 + col] = o;
            }
        }
#pragma unroll
        for (int p = 0; p < 4; p++) {
            int krow = p*8 + tid/32, ncol = (tid & 31) * 4;
            float4 v = *(const float4*)&Bw[(size_t)(k0 + krow) * Ndim + n0 + ncol];
            sB[(ncol + 0)*32 + krow] = f2bf(v.x);
            sB[(ncol + 1)*32 + krow] = f2bf(v.y);
            sB[(ncol + 2)*32 + krow] = f2bf(v.z);
            sB[(ncol + 3)*32 + krow] = f2bf(v.w);
        }
        __syncthreads();
        bf16x8 af[4], bfj[4];
#pragma unroll
        for (int i = 0; i < 4; i++)
            af[i]  = *(const bf16x8*)&sA[(wr*64 + i*16 + lrow)*32 + lk];
#pragma unroll
        for (int j = 0; j < 4; j++)
            bfj[j] = *(const bf16x8*)&sB[(wc*64 + j*16 + lrow)*32 + lk];
#pragma unroll
        for (int i = 0; i < 4; i++)
#pragma unroll
            for (int j = 0; j < 4; j++)
                acc[i][j] = __builtin_amdgcn_mfma_f32_16x16x32_bf16(af[i], bfj[j], acc[i][j], 0, 0, 0);
        __syncthreads();
    }

    if (MODE == 0) {
#pragma unroll
        for (int i = 0; i < 4; i++) {
#pragma unroll
            for (int j = 0; j < 4; j++) {
                int col = n0 + wc*64 + j*16 + lrow;
                float bv = bias[col];
#pragma unroll
                for (int r = 0; r < 4; r++) {
                    int row = m0 + wr*64 + i*16 + (lane >> 4)*4 + r;
                    ((float*)out0)[(size_t)row * Ndim + col] = acc[i][j][r] + bv;
                }
            }
        }
    } else {
        const int t = n0 >> 7, part = t % 3, h = t / 3;
        float bv[4];
#pragma unroll
        for (int j = 0; j < 4; j++)
            bv[j] = bias[n0 + wc*64 + j*16 + lrow];

#pragma unroll
        for (int i = 0; i < 4; i++) {
            const int rowb = m0 + wr*64 + i*16 + (lane >> 4)*4;  // multiple of 4
            const int b = rowb >> 11, sbase = rowb & 2047;       // r=0..3 same b
            if (part == 2) {
                size_t vb = ((size_t)(b*H_ + h)) * HD_ * S_;
#pragma unroll
                for (int j = 0; j < 4; j++) {
                    int d = wc*64 + j*16 + lrow;
                    ushort4 o;
                    o.x = f2bf(acc[i][j][0] + bv[j]);
                    o.y = f2bf(acc[i][j][1] + bv[j]);
                    o.z = f2bf(acc[i][j][2] + bv[j]);
                    o.w = f2bf(acc[i][j][3] + bv[j]);
                    *(ushort4*)&out2[vb + (size_t)d * S_ + sbase] = o;
                }
            } else {
                unsigned short* outp = (part == 0) ? (unsigned short*)out0 : out1;
                size_t qb = ((size_t)(b*H_ + h)) * S_ * HD_;
#pragma unroll
                for (int r = 0; r < 4; r++) {
                    int s = sbase + r;
                    float vals[4];
#pragma unroll
                    for (int j = 0; j < 4; j++)
                        vals[j] = acc[i][j][r] + bv[j];
                    if (wc == 0) {
                        float inv = exp2f(-(float)lrow * 0.8304817737218413f); // 10000^(-lrow/16)
                        float ang = (float)s * inv, sn, cs;
                        sincosf(ang, &sn, &cs);
                        float v0 = vals[0]*cs - vals[1]*sn;   // d<16:  x*cos - x[d+16]*sin
                        float v1 = vals[1]*cs + vals[0]*sn;   // d>=16: x*cos + x[d-16]*sin
                        vals[0] = v0; vals[1] = v1;
                    }
#pragma unroll
                    for (int j = 0; j < 4; j++)
                        outp[qb + (size_t)s * HD_ + wc*64 + j*16 + lrow] = f2bf(vals[j]);
                }
            }
        }
    }
}

// ---------------------------------------------------------------- flash attention v2
// MFMA QK^T and PV; softmax/mask/state in PLAIN LDS [q][k] space (no
// fragment-layout assumptions in the softmax path). One owner lane per q-row.
// Q,K: [bh][s][d] bf16; Vt: [bh][d][s] bf16; ctx: [b][s][h*HD+d] bf16.
__global__ __launch_bounds__(256) void flash2_kernel(
    const unsigned short* __restrict__ Qg,
    const unsigned short* __restrict__ Kg,
    const unsigned short* __restrict__ Vt,
    unsigned short* __restrict__ ctx)
{
    __shared__ unsigned short sK[64 * 128];   // K tile [key][d] (also Q staging)
    __shared__ unsigned short sVt[128 * 64];  // V^T tile [d][key]
    __shared__ float          sS[64 * 65];    // fp32 scores [q][k], padded
    __shared__ unsigned short sP[64 * 72];    // bf16 probs [q][k], padded (16B-aligned rows)
    __shared__ float sM[64], sL[64], sAl[64]; // per-row online-softmax state

    const int tid = threadIdx.x, lane = tid & 63, wave = tid >> 6;
    const int bh = blockIdx.y, q0 = blockIdx.x * 64;
    const int b = bh / H_, h = bh % H_;
    const unsigned short* Qb = Qg + (size_t)bh * S_ * HD_;
    const unsigned short* Kb = Kg + (size_t)bh * S_ * HD_;
    const unsigned short* Vb = Vt + (size_t)bh * HD_ * S_;
    const int lrow = lane & 15, quad = lane >> 4, lk = quad * 8;

    // row owners: wave w, lanes 0..15 own local rows w*16 + lrow
    if (lane < 16) { sM[wave*16 + lrow] = -1e30f; sL[wave*16 + lrow] = 0.f; }

    // stage Q tile (64x128) via sK, pull this wave's 16 rows into A-fragments
#pragma unroll
    for (int c = 0; c < 4; c++)
        GLDS(Qb + (size_t)(q0 + c*16 + tid/16) * HD_ + (tid & 15)*8, sK + c*2048 + tid*8);
    __syncthreads();
    bf16x8 qf[4];
#pragma unroll
    for (int c = 0; c < 4; c++)
        qf[c] = *(const bf16x8*)&sK[(wave*16 + lrow)*128 + c*32 + lk];
    __syncthreads();

    f32x4 O[8] = {};

    const int ktiles = blockIdx.x + 1;
    for (int kt = 0; kt < ktiles; kt++) {
        const int ks = kt * 64;
#pragma unroll
        for (int c = 0; c < 4; c++)
            GLDS(Kb + (size_t)(ks + c*16 + tid/16) * HD_ + (tid & 15)*8, sK  + c*2048 + tid*8);
#pragma unroll
        for (int c = 0; c < 4; c++)
            GLDS(Vb + (size_t)(c*32 + tid/8) * S_ + ks + (tid & 7)*8,   sVt + c*2048 + tid*8);
        __syncthreads();

        // S = Q K^T (each wave: its 16 q-rows x 64 keys), write to sS in
        // plain [q][k] with scale+causal mask (verified C-layout write pattern)
        f32x4 sc[4] = {};
#pragma unroll
        for (int j = 0; j < 4; j++)
#pragma unroll
            for (int c = 0; c < 4; c++) {
                bf16x8 kf = *(const bf16x8*)&sK[(j*16 + lrow)*128 + c*32 + lk];
                sc[j] = __builtin_amdgcn_mfma_f32_16x16x32_bf16(qf[c], kf, sc[j], 0, 0, 0);
            }
#pragma unroll
        for (int j = 0; j < 4; j++) {
            const int kcol = j*16 + lrow;
#pragma unroll
            for (int r = 0; r < 4; r++) {
                const int qrow = wave*16 + quad*4 + r;
                float v = sc[j][r] * SCALE_;
                sS[qrow*65 + kcol] = (ks + kcol <= q0 + qrow) ? v : -1e30f;
            }
        }
        __syncthreads();

        // per-row online softmax by owner lanes (plain indexing)
        if (lane < 16) {
            const int row = wave*16 + lrow;
            float mprev = sM[row];
            float tm = -1e30f;
#pragma unroll 8
            for (int k = 0; k < 64; k++) tm = fmaxf(tm, sS[row*65 + k]);
            float mn = fmaxf(mprev, tm);
            float alpha = __expf(mprev - mn);
            float sum = 0.f;
#pragma unroll 8
            for (int k = 0; k < 64; k++) {
                float p = __expf(sS[row*65 + k] - mn);
                sum += p;
                sP[row*72 + k] = f2bf(p);
            }
            sM[row] = mn;
            sL[row] = sL[row]*alpha + sum;
            sAl[row] = alpha;
        }
        __syncthreads();

        // rescale O, then O += P V
        float al[4];
#pragma unroll
        for (int r = 0; r < 4; r++) al[r] = sAl[wave*16 + quad*4 + r];
#pragma unroll
        for (int jo = 0; jo < 8; jo++)
#pragma unroll
            for (int r = 0; r < 4; r++) O[jo][r] *= al[r];
#pragma unroll
        for (int c = 0; c < 2; c++) {
            bf16x8 pf = *(const bf16x8*)&sP[(wave*16 + lrow)*72 + c*32 + lk];
#pragma unroll
            for (int jo = 0; jo < 8; jo++) {
                bf16x8 vf = *(const bf16x8*)&sVt[(jo*16 + lrow)*64 + c*32 + lk];
                O[jo] = __builtin_amdgcn_mfma_f32_16x16x32_bf16(pf, vf, O[jo], 0, 0, 0);
            }
        }
        __syncthreads();  // before next tile's GLDS overwrites sK/sVt
    }

    // epilogue: O /= l, write ctx[b][s][h*128+d]
    float li[4];
#pragma unroll
    for (int r = 0; r < 4; r++) li[r] = sL[wave*16 + quad*4 + r];
#pragma unroll
    for (int jo = 0; jo < 8; jo++) {
        const int dcol = jo*16 + lrow;
#pragma unroll
        for (int r = 0; r < 4; r++) {
            const int srow = q0 + wave*16 + quad*4 + r;
            ctx[((size_t)b * S_ + srow) * D_ + h*HD_ + dcol] = f2bf(O[jo][r] / li[r]);
        }
    }
}

// ---------------------------------------------------------------- launch
extern "C" void kernel_launch(void* const* d_in, const int* in_sizes, int n_in,
                              void* d_out, int out_size, void* d_ws, size_t ws_size,
                              hipStream_t stream) {
    const float* hs   = (const float*)d_in[0];
    // d_in[1] attention_mask: all ones, unused by the reference math
    const float* Wqkv = (const float*)d_in[2];
    const float* bqkv = (const float*)d_in[3];
    const float* Wd   = (const float*)d_in[4];
    const float* bd   = (const float*)d_in[5];
    float* out = (float*)d_out;

    char* ws  = (char*)d_ws;
    char* dob = (char*)d_out;
    // Memory map (verified in round 4; peak d_ws use: 32 MiB):
    //   ws[0,16MiB):   Vt  [bh][d][s] bf16
    //   ws[16,32MiB):  ctx [b][s][h*hd] bf16
    //   d_out[0,16MiB):  Qg [bh][s][d] bf16   (dead before gemm2 writes)
    //   d_out[16,32MiB): Kg [bh][s][d] bf16
    unsigned short* Vt  = (unsigned short*)(ws);
    unsigned short* ctx = (unsigned short*)(ws + 16777216);
    unsigned short* Qg  = (unsigned short*)(dob);
    unsigned short* Kg  = (unsigned short*)(dob + 16777216);

    // 1. fused QKV projection + bias + RoPE + head-split (+ V transpose)
    gemmf_kernel<0, 1><<<dim3(N3_/128, M_/128), dim3(256), 0, stream>>>(
        hs, Wqkv, bqkv, Qg, Kg, Vt, N3_, D_);
    // 2. causal flash attention (MFMA, plain-LDS softmax)
    flash2_kernel<<<dim3(S_/64, B_*H_), dim3(256), 0, stream>>>(Qg, Kg, Vt, ctx);
    // 3. dense projection, fp32 out
    gemmf_kernel<1, 0><<<dim3(D_/128, M_/128), dim3(256), 0, stream>>>(
        ctx, Wd, bd, out, nullptr, nullptr, D_, D_);
}

// Round 6
// 964.968 us; speedup vs baseline: 7.3644x; 1.7938x over previous
//
#include <hip/hip_runtime.h>
#include <hip/hip_bf16.h>
#include <math.h>

#define B_   2
#define S_   2048
#define D_   2048
#define H_   16
#define HD_  128
#define ROT_ 32
#define M_   (B_*S_)    // 4096 tokens
#define N3_  (3*D_)     // 6144

static constexpr float SCALE_ = 0.08838834764831845f;  // 1/sqrt(128)

typedef __attribute__((ext_vector_type(4))) float  f32x4;
typedef __attribute__((ext_vector_type(8))) __bf16 bf16x8;

__device__ inline unsigned short f2bf(float f) {
    unsigned int u = __builtin_bit_cast(unsigned int, f);
    unsigned int r = (u + 0x7fffu + ((u >> 16) & 1u)) >> 16;
    return (unsigned short)r;
}
__device__ inline float bf2f(unsigned short h) {
    unsigned int u = ((unsigned int)h) << 16;
    return __builtin_bit_cast(float, u);
}

#define GLDS(g, l) __builtin_amdgcn_global_load_lds(                          \
    (const __attribute__((address_space(1))) void*)(g),                       \
    (__attribute__((address_space(3))) void*)(l), 16, 0, 0)

// ------------------------------------------- transpose+cast (conflict-free)
// src: R x ldS fp32 (use a 2048-col window starting at src);
// dst: 2048 x R bf16 with dst[c][r] = src[r][c].
__global__ __launch_bounds__(256) void transpose_cast_kernel(
    const float* __restrict__ src, unsigned short* __restrict__ dst,
    int R, int ldS)
{
    __shared__ float tile[32][33];
    int c0 = blockIdx.x * 32, r0 = blockIdx.y * 32;
    int tx = threadIdx.x & 31, ty = threadIdx.x >> 5;  // ty 0..7
#pragma unroll
    for (int i = 0; i < 4; i++)
        tile[ty + i*8][tx] = src[(size_t)(r0 + ty + i*8) * ldS + c0 + tx];
    __syncthreads();
#pragma unroll
    for (int i = 0; i < 4; i++)
        dst[(size_t)(c0 + ty + i*8) * R + r0 + tx] = f2bf(tile[tx][ty + i*8]);
}

// ---------------------------------------------------------------- GEMM (B^T, GLDS both sides)
// C = A @ B + bias. A: M x K row-major (fp32 if ABF16==0 -> register cast;
// bf16 if ABF16==1 -> GLDS). BT: bf16 [n_local][K] (pre-transposed chunk).
// n0_global = n_base + blockIdx.x*128 for bias/epilogue; BT indexed locally.
// MODE 0: fp32 C (+bias) -> out0 (stride Ndim).
// MODE 1: qkv epilogue (bias + RoPE + head-split scatter; RoPE partner of
//         d<32 lives in acc[i][j^1][r] of the same lane). [verified r4]
template <int ABF16, int MODE>
__global__ __launch_bounds__(256) void gemm_bt2_kernel(
    const void* __restrict__ Aptr,
    const unsigned short* __restrict__ BT,
    const float* __restrict__ bias,
    void* __restrict__ out0,
    unsigned short* __restrict__ out1,
    unsigned short* __restrict__ out2,
    int Ndim, int K, int n_base)
{
    __shared__ unsigned short sA[128 * 32];
    __shared__ unsigned short sB[128 * 32];
    const int tid  = threadIdx.x;
    const int m0   = blockIdx.y * 128;
    const int nloc = blockIdx.x * 128;          // local row in BT
    const int n0   = n_base + nloc;             // global output column base
    const int lane = tid & 63, wave = tid >> 6;
    const int wr = wave >> 1, wc = wave & 1;
    const int lrow = lane & 15, lk = (lane >> 4) * 8;

    f32x4 acc[4][4] = {};

    const unsigned short* Bg = BT + (size_t)(nloc + tid/4) * K + (tid & 3) * 8;

    for (int k0 = 0; k0 < K; k0 += 32) {
        if (ABF16) {
            const unsigned short* Ab = (const unsigned short*)Aptr;
#pragma unroll
            for (int c = 0; c < 2; c++)
                GLDS(Ab + (size_t)(m0 + c*64 + tid/4) * K + k0 + (tid & 3) * 8,
                     sA + c*2048 + tid*8);
        } else {
            const float* Af = (const float*)Aptr;
#pragma unroll
            for (int p = 0; p < 4; p++) {
                int row = p*32 + tid/8, col = (tid & 7) * 4;
                float4 v = *(const float4*)&Af[(size_t)(m0 + row) * K + k0 + col];
                ushort4 o;
                o.x = f2bf(v.x); o.y = f2bf(v.y); o.z = f2bf(v.z); o.w = f2bf(v.w);
                *(ushort4*)&sA[row*32 + col] = o;
            }
        }
#pragma unroll
        for (int c = 0; c < 2; c++)
            GLDS(Bg + (size_t)c*64*K + k0, sB + c*2048 + tid*8);
        __syncthreads();
        bf16x8 af[4], bfj[4];
#pragma unroll
        for (int i = 0; i < 4; i++)
            af[i]  = *(const bf16x8*)&sA[(wr*64 + i*16 + lrow)*32 + lk];
#pragma unroll
        for (int j = 0; j < 4; j++)
            bfj[j] = *(const bf16x8*)&sB[(wc*64 + j*16 + lrow)*32 + lk];
#pragma unroll
        for (int i = 0; i < 4; i++)
#pragma unroll
            for (int j = 0; j < 4; j++)
                acc[i][j] = __builtin_amdgcn_mfma_f32_16x16x32_bf16(af[i], bfj[j], acc[i][j], 0, 0, 0);
        __syncthreads();
    }

    if (MODE == 0) {
#pragma unroll
        for (int i = 0; i < 4; i++) {
#pragma unroll
            for (int j = 0; j < 4; j++) {
                int col = n0 + wc*64 + j*16 + lrow;
                float bv = bias[col];
#pragma unroll
                for (int r = 0; r < 4; r++) {
                    int row = m0 + wr*64 + i*16 + (lane >> 4)*4 + r;
                    ((float*)out0)[(size_t)row * Ndim + col] = acc[i][j][r] + bv;
                }
            }
        }
    } else {
        const int t = n0 >> 7, part = t % 3, h = t / 3;
        float bv[4];
#pragma unroll
        for (int j = 0; j < 4; j++)
            bv[j] = bias[n0 + wc*64 + j*16 + lrow];

#pragma unroll
        for (int i = 0; i < 4; i++) {
            const int rowb = m0 + wr*64 + i*16 + (lane >> 4)*4;  // multiple of 4
            const int b = rowb >> 11, sbase = rowb & 2047;       // r=0..3 same b
            if (part == 2) {
                size_t vb = ((size_t)(b*H_ + h)) * HD_ * S_;
#pragma unroll
                for (int j = 0; j < 4; j++) {
                    int d = wc*64 + j*16 + lrow;
                    ushort4 o;
                    o.x = f2bf(acc[i][j][0] + bv[j]);
                    o.y = f2bf(acc[i][j][1] + bv[j]);
                    o.z = f2bf(acc[i][j][2] + bv[j]);
                    o.w = f2bf(acc[i][j][3] + bv[j]);
                    *(ushort4*)&out2[vb + (size_t)d * S_ + sbase] = o;
                }
            } else {
                unsigned short* outp = (part == 0) ? (unsigned short*)out0 : out1;
                size_t qb = ((size_t)(b*H_ + h)) * S_ * HD_;
#pragma unroll
                for (int r = 0; r < 4; r++) {
                    int s = sbase + r;
                    float vals[4];
#pragma unroll
                    for (int j = 0; j < 4; j++)
                        vals[j] = acc[i][j][r] + bv[j];
                    if (wc == 0) {
                        float inv = exp2f(-(float)lrow * 0.8304817737218413f); // 10000^(-lrow/16)
                        float ang = (float)s * inv, sn, cs;
                        sincosf(ang, &sn, &cs);
                        float v0 = vals[0]*cs - vals[1]*sn;   // d<16:  x*cos - x[d+16]*sin
                        float v1 = vals[1]*cs + vals[0]*sn;   // d>=16: x*cos + x[d-16]*sin
                        vals[0] = v0; vals[1] = v1;
                    }
#pragma unroll
                    for (int j = 0; j < 4; j++)
                        outp[qb + (size_t)s * HD_ + wc*64 + j*16 + lrow] = f2bf(vals[j]);
                }
            }
        }
    }
}

// ---------------------------------------------------------------- flash attention v2
// (VERIFIED round 5 — unchanged)
__global__ __launch_bounds__(256) void flash2_kernel(
    const unsigned short* __restrict__ Qg,
    const unsigned short* __restrict__ Kg,
    const unsigned short* __restrict__ Vt,
    unsigned short* __restrict__ ctx)
{
    __shared__ unsigned short sK[64 * 128];   // K tile [key][d] (also Q staging)
    __shared__ unsigned short sVt[128 * 64];  // V^T tile [d][key]
    __shared__ float          sS[64 * 65];    // fp32 scores [q][k], padded
    __shared__ unsigned short sP[64 * 72];    // bf16 probs [q][k], padded
    __shared__ float sM[64], sL[64], sAl[64]; // per-row online-softmax state

    const int tid = threadIdx.x, lane = tid & 63, wave = tid >> 6;
    const int bh = blockIdx.y, q0 = blockIdx.x * 64;
    const int b = bh / H_, h = bh % H_;
    const unsigned short* Qb = Qg + (size_t)bh * S_ * HD_;
    const unsigned short* Kb = Kg + (size_t)bh * S_ * HD_;
    const unsigned short* Vb = Vt + (size_t)bh * HD_ * S_;
    const int lrow = lane & 15, quad = lane >> 4, lk = quad * 8;

    if (lane < 16) { sM[wave*16 + lrow] = -1e30f; sL[wave*16 + lrow] = 0.f; }

#pragma unroll
    for (int c = 0; c < 4; c++)
        GLDS(Qb + (size_t)(q0 + c*16 + tid/16) * HD_ + (tid & 15)*8, sK + c*2048 + tid*8);
    __syncthreads();
    bf16x8 qf[4];
#pragma unroll
    for (int c = 0; c < 4; c++)
        qf[c] = *(const bf16x8*)&sK[(wave*16 + lrow)*128 + c*32 + lk];
    __syncthreads();

    f32x4 O[8] = {};

    const int ktiles = blockIdx.x + 1;
    for (int kt = 0; kt < ktiles; kt++) {
        const int ks = kt * 64;
#pragma unroll
        for (int c = 0; c < 4; c++)
            GLDS(Kb + (size_t)(ks + c*16 + tid/16) * HD_ + (tid & 15)*8, sK  + c*2048 + tid*8);
#pragma unroll
        for (int c = 0; c < 4; c++)
            GLDS(Vb + (size_t)(c*32 + tid/8) * S_ + ks + (tid & 7)*8,   sVt + c*2048 + tid*8);
        __syncthreads();

        f32x4 sc[4] = {};
#pragma unroll
        for (int j = 0; j < 4; j++)
#pragma unroll
            for (int c = 0; c < 4; c++) {
                bf16x8 kf = *(const bf16x8*)&sK[(j*16 + lrow)*128 + c*32 + lk];
                sc[j] = __builtin_amdgcn_mfma_f32_16x16x32_bf16(qf[c], kf, sc[j], 0, 0, 0);
            }
#pragma unroll
        for (int j = 0; j < 4; j++) {
            const int kcol = j*16 + lrow;
#pragma unroll
            for (int r = 0; r < 4; r++) {
                const int qrow = wave*16 + quad*4 + r;
                float v = sc[j][r] * SCALE_;
                sS[qrow*65 + kcol] = (ks + kcol <= q0 + qrow) ? v : -1e30f;
            }
        }
        __syncthreads();

        if (lane < 16) {
            const int row = wave*16 + lrow;
            float mprev = sM[row];
            float tm = -1e30f;
#pragma unroll 8
            for (int k = 0; k < 64; k++) tm = fmaxf(tm, sS[row*65 + k]);
            float mn = fmaxf(mprev, tm);
            float alpha = __expf(mprev - mn);
            float sum = 0.f;
#pragma unroll 8
            for (int k = 0; k < 64; k++) {
                float p = __expf(sS[row*65 + k] - mn);
                sum += p;
                sP[row*72 + k] = f2bf(p);
            }
            sM[row] = mn;
            sL[row] = sL[row]*alpha + sum;
            sAl[row] = alpha;
        }
        __syncthreads();

        float al[4];
#pragma unroll
        for (int r = 0; r < 4; r++) al[r] = sAl[wave*16 + quad*4 + r];
#pragma unroll
        for (int jo = 0; jo < 8; jo++)
#pragma unroll
            for (int r = 0; r < 4; r++) O[jo][r] *= al[r];
#pragma unroll
        for (int c = 0; c < 2; c++) {
            bf16x8 pf = *(const bf16x8*)&sP[(wave*16 + lrow)*72 + c*32 + lk];
#pragma unroll
            for (int jo = 0; jo < 8; jo++) {
                bf16x8 vf = *(const bf16x8*)&sVt[(jo*16 + lrow)*64 + c*32 + lk];
                O[jo] = __builtin_amdgcn_mfma_f32_16x16x32_bf16(pf, vf, O[jo], 0, 0, 0);
            }
        }
        __syncthreads();
    }

    float li[4];
#pragma unroll
    for (int r = 0; r < 4; r++) li[r] = sL[wave*16 + quad*4 + r];
#pragma unroll
    for (int jo = 0; jo < 8; jo++) {
        const int dcol = jo*16 + lrow;
#pragma unroll
        for (int r = 0; r < 4; r++) {
            const int srow = q0 + wave*16 + quad*4 + r;
            ctx[((size_t)b * S_ + srow) * D_ + h*HD_ + dcol] = f2bf(O[jo][r] / li[r]);
        }
    }
}

// ---------------------------------------------------------------- launch
extern "C" void kernel_launch(void* const* d_in, const int* in_sizes, int n_in,
                              void* d_out, int out_size, void* d_ws, size_t ws_size,
                              hipStream_t stream) {
    const float* hs   = (const float*)d_in[0];
    // d_in[1] attention_mask: all ones, unused by the reference math
    const float* Wqkv = (const float*)d_in[2];
    const float* bqkv = (const float*)d_in[3];
    const float* Wd   = (const float*)d_in[4];
    const float* bd   = (const float*)d_in[5];
    float* out = (float*)d_out;

    char* ws  = (char*)d_ws;
    char* dob = (char*)d_out;
    // Memory map (peak d_ws use: 32 MiB, verified r4/r5):
    //   ws[0,16MiB):   Vt [bh][d][s] bf16 (gemm1 out);  WdT at ws[0,8MiB)
    //                  after flash (Vt dead).
    //   ws[16,24MiB):  TW — per-chunk W^T bf16 during gemm1; dead before ctx.
    //   ws[16,32MiB):  ctx [b][s][h*hd] bf16 (flash out -> gemm2 A).
    //   d_out[0,16MiB):  Qg ; d_out[16,32MiB): Kg  (dead before gemm2 writes)
    unsigned short* Vt  = (unsigned short*)(ws);
    unsigned short* WdT = (unsigned short*)(ws);
    unsigned short* TW  = (unsigned short*)(ws + 16777216);
    unsigned short* ctx = (unsigned short*)(ws + 16777216);
    unsigned short* Qg  = (unsigned short*)(dob);
    unsigned short* Kg  = (unsigned short*)(dob + 16777216);

    // 1. QKV projection in 3 column-chunks of 2048: transpose chunk -> GEMM
    for (int c = 0; c < 3; c++) {
        transpose_cast_kernel<<<dim3(64, 64), dim3(256), 0, stream>>>(
            Wqkv + c*2048, TW, D_, N3_);
        gemm_bt2_kernel<0, 1><<<dim3(16, 32), dim3(256), 0, stream>>>(
            hs, TW, bqkv, Qg, Kg, Vt, N3_, D_, c*2048);
    }
    // 2. causal flash attention (MFMA, plain-LDS softmax) [verified r5]
    flash2_kernel<<<dim3(S_/64, B_*H_), dim3(256), 0, stream>>>(Qg, Kg, Vt, ctx);
    // 3. W_dense^T (Vt region now dead), then dense projection, fp32 out
    transpose_cast_kernel<<<dim3(64, 64), dim3(256), 0, stream>>>(
        Wd, WdT, D_, D_);
    gemm_bt2_kernel<1, 0><<<dim3(16, 32), dim3(256), 0, stream>>>(
        ctx, WdT, bd, out, nullptr, nullptr, D_, D_, 0);
}

// Round 7
// 618.547 us; speedup vs baseline: 11.4889x; 1.5601x over previous
//
#include <hip/hip_runtime.h>
#include <hip/hip_bf16.h>
#include <math.h>

#define B_   2
#define S_   2048
#define D_   2048
#define H_   16
#define HD_  128
#define ROT_ 32
#define M_   (B_*S_)    // 4096 tokens
#define N3_  (3*D_)     // 6144

static constexpr float SCALE_ = 0.08838834764831845f;  // 1/sqrt(128)

typedef __attribute__((ext_vector_type(4))) float  f32x4;
typedef __attribute__((ext_vector_type(8))) __bf16 bf16x8;

__device__ inline unsigned short f2bf(float f) {
    unsigned int u = __builtin_bit_cast(unsigned int, f);
    unsigned int r = (u + 0x7fffu + ((u >> 16) & 1u)) >> 16;
    return (unsigned short)r;
}
__device__ inline float bf2f(unsigned short h) {
    unsigned int u = ((unsigned int)h) << 16;
    return __builtin_bit_cast(float, u);
}

#define GLDS(g, l) __builtin_amdgcn_global_load_lds(                          \
    (const __attribute__((address_space(1))) void*)(g),                       \
    (__attribute__((address_space(3))) void*)(l), 16, 0, 0)

// ---------------------------------------------------------------- cast fp32 -> bf16
__global__ void cast_bf16_kernel(const float* __restrict__ src,
                                 unsigned short* __restrict__ dst, int n4) {
    int i = blockIdx.x * blockDim.x + threadIdx.x;
    if (i < n4) {
        float4 v = ((const float4*)src)[i];
        ushort4 o;
        o.x = f2bf(v.x); o.y = f2bf(v.y); o.z = f2bf(v.z); o.w = f2bf(v.w);
        ((ushort4*)dst)[i] = o;
    }
}

// ------------------------------------------- transpose+cast (conflict-free)
__global__ __launch_bounds__(256) void transpose_cast_kernel(
    const float* __restrict__ src, unsigned short* __restrict__ dst,
    int R, int ldS)
{
    __shared__ float tile[32][33];
    int c0 = blockIdx.x * 32, r0 = blockIdx.y * 32;
    int tx = threadIdx.x & 31, ty = threadIdx.x >> 5;  // ty 0..7
#pragma unroll
    for (int i = 0; i < 4; i++)
        tile[ty + i*8][tx] = src[(size_t)(r0 + ty + i*8) * ldS + c0 + tx];
    __syncthreads();
#pragma unroll
    for (int i = 0; i < 4; i++)
        dst[(size_t)(c0 + ty + i*8) * R + r0 + tx] = f2bf(tile[tx][ty + i*8]);
}

// ---------------------------------------------------------------- GEMM (B^T, GLDS both sides)
// (verified r6) C = A @ B + bias. A: M x K row-major (fp32->register cast if
// ABF16==0; bf16 GLDS if 1). BT: bf16 [n_local][K]. n0 = n_base + bx*128.
// MODE 0: fp32 C (+bias). MODE 1: qkv epilogue (bias+RoPE+head-split scatter).
template <int ABF16, int MODE>
__global__ __launch_bounds__(256) void gemm_bt2_kernel(
    const void* __restrict__ Aptr,
    const unsigned short* __restrict__ BT,
    const float* __restrict__ bias,
    void* __restrict__ out0,
    unsigned short* __restrict__ out1,
    unsigned short* __restrict__ out2,
    int Ndim, int K, int n_base)
{
    __shared__ unsigned short sA[128 * 32];
    __shared__ unsigned short sB[128 * 32];
    const int tid  = threadIdx.x;
    const int m0   = blockIdx.y * 128;
    const int nloc = blockIdx.x * 128;
    const int n0   = n_base + nloc;
    const int lane = tid & 63, wave = tid >> 6;
    const int wr = wave >> 1, wc = wave & 1;
    const int lrow = lane & 15, lk = (lane >> 4) * 8;

    f32x4 acc[4][4] = {};

    const unsigned short* Bg = BT + (size_t)(nloc + tid/4) * K + (tid & 3) * 8;

    for (int k0 = 0; k0 < K; k0 += 32) {
        if (ABF16) {
            const unsigned short* Ab = (const unsigned short*)Aptr;
#pragma unroll
            for (int c = 0; c < 2; c++)
                GLDS(Ab + (size_t)(m0 + c*64 + tid/4) * K + k0 + (tid & 3) * 8,
                     sA + c*2048 + tid*8);
        } else {
            const float* Af = (const float*)Aptr;
#pragma unroll
            for (int p = 0; p < 4; p++) {
                int row = p*32 + tid/8, col = (tid & 7) * 4;
                float4 v = *(const float4*)&Af[(size_t)(m0 + row) * K + k0 + col];
                ushort4 o;
                o.x = f2bf(v.x); o.y = f2bf(v.y); o.z = f2bf(v.z); o.w = f2bf(v.w);
                *(ushort4*)&sA[row*32 + col] = o;
            }
        }
#pragma unroll
        for (int c = 0; c < 2; c++)
            GLDS(Bg + (size_t)c*64*K + k0, sB + c*2048 + tid*8);
        __syncthreads();
        bf16x8 af[4], bfj[4];
#pragma unroll
        for (int i = 0; i < 4; i++)
            af[i]  = *(const bf16x8*)&sA[(wr*64 + i*16 + lrow)*32 + lk];
#pragma unroll
        for (int j = 0; j < 4; j++)
            bfj[j] = *(const bf16x8*)&sB[(wc*64 + j*16 + lrow)*32 + lk];
#pragma unroll
        for (int i = 0; i < 4; i++)
#pragma unroll
            for (int j = 0; j < 4; j++)
                acc[i][j] = __builtin_amdgcn_mfma_f32_16x16x32_bf16(af[i], bfj[j], acc[i][j], 0, 0, 0);
        __syncthreads();
    }

    if (MODE == 0) {
#pragma unroll
        for (int i = 0; i < 4; i++) {
#pragma unroll
            for (int j = 0; j < 4; j++) {
                int col = n0 + wc*64 + j*16 + lrow;
                float bv = bias[col];
#pragma unroll
                for (int r = 0; r < 4; r++) {
                    int row = m0 + wr*64 + i*16 + (lane >> 4)*4 + r;
                    ((float*)out0)[(size_t)row * Ndim + col] = acc[i][j][r] + bv;
                }
            }
        }
    } else {
        const int t = n0 >> 7, part = t % 3, h = t / 3;
        float bv[4];
#pragma unroll
        for (int j = 0; j < 4; j++)
            bv[j] = bias[n0 + wc*64 + j*16 + lrow];

#pragma unroll
        for (int i = 0; i < 4; i++) {
            const int rowb = m0 + wr*64 + i*16 + (lane >> 4)*4;
            const int b = rowb >> 11, sbase = rowb & 2047;
            if (part == 2) {
                size_t vb = ((size_t)(b*H_ + h)) * HD_ * S_;
#pragma unroll
                for (int j = 0; j < 4; j++) {
                    int d = wc*64 + j*16 + lrow;
                    ushort4 o;
                    o.x = f2bf(acc[i][j][0] + bv[j]);
                    o.y = f2bf(acc[i][j][1] + bv[j]);
                    o.z = f2bf(acc[i][j][2] + bv[j]);
                    o.w = f2bf(acc[i][j][3] + bv[j]);
                    *(ushort4*)&out2[vb + (size_t)d * S_ + sbase] = o;
                }
            } else {
                unsigned short* outp = (part == 0) ? (unsigned short*)out0 : out1;
                size_t qb = ((size_t)(b*H_ + h)) * S_ * HD_;
#pragma unroll
                for (int r = 0; r < 4; r++) {
                    int s = sbase + r;
                    float vals[4];
#pragma unroll
                    for (int j = 0; j < 4; j++)
                        vals[j] = acc[i][j][r] + bv[j];
                    if (wc == 0) {
                        float inv = exp2f(-(float)lrow * 0.8304817737218413f); // 10000^(-lrow/16)
                        float ang = (float)s * inv, sn, cs;
                        sincosf(ang, &sn, &cs);
                        float v0 = vals[0]*cs - vals[1]*sn;
                        float v1 = vals[1]*cs + vals[0]*sn;
                        vals[0] = v0; vals[1] = v1;
                    }
#pragma unroll
                    for (int j = 0; j < 4; j++)
                        outp[qb + (size_t)s * HD_ + wc*64 + j*16 + lrow] = f2bf(vals[j]);
                }
            }
        }
    }
}

// ---------------------------------------------------------------- flash attention v3
// v2 (verified r5) + parallel wave-private softmax, 2 barriers/tile.
// sS/sP/sM/sL/sAl are wave-private (each wave touches only its 16 rows);
// LDS ops within a wave execute in program order -> no barrier needed there.
__global__ __launch_bounds__(256) void flash3_kernel(
    const unsigned short* __restrict__ Qg,
    const unsigned short* __restrict__ Kg,
    const unsigned short* __restrict__ Vt,
    unsigned short* __restrict__ ctx)
{
    __shared__ unsigned short sK[64 * 128];   // K tile [key][d] (also Q staging)
    __shared__ unsigned short sVt[128 * 64];  // V^T tile [d][key]
    __shared__ float          sS[64 * 65];    // fp32 scores [q][k], padded
    __shared__ unsigned short sP[64 * 72];    // bf16 probs [q][k], padded
    __shared__ float sM[64], sL[64], sAl[64]; // per-row online-softmax state

    const int tid = threadIdx.x, lane = tid & 63, wave = tid >> 6;
    const int bh = blockIdx.y, q0 = blockIdx.x * 64;
    const int b = bh / H_, h = bh % H_;
    const unsigned short* Qb = Qg + (size_t)bh * S_ * HD_;
    const unsigned short* Kb = Kg + (size_t)bh * S_ * HD_;
    const unsigned short* Vb = Vt + (size_t)bh * HD_ * S_;
    const int lrow = lane & 15, quad = lane >> 4, lk = quad * 8;

    if (quad == 0) { sM[wave*16 + lrow] = -1e30f; sL[wave*16 + lrow] = 0.f; }

#pragma unroll
    for (int c = 0; c < 4; c++)
        GLDS(Qb + (size_t)(q0 + c*16 + tid/16) * HD_ + (tid & 15)*8, sK + c*2048 + tid*8);
    __syncthreads();
    bf16x8 qf[4];
#pragma unroll
    for (int c = 0; c < 4; c++)
        qf[c] = *(const bf16x8*)&sK[(wave*16 + lrow)*128 + c*32 + lk];
    __syncthreads();

    f32x4 O[8] = {};

    const int ktiles = blockIdx.x + 1;
    for (int kt = 0; kt < ktiles; kt++) {
        const int ks = kt * 64;
#pragma unroll
        for (int c = 0; c < 4; c++)
            GLDS(Kb + (size_t)(ks + c*16 + tid/16) * HD_ + (tid & 15)*8, sK  + c*2048 + tid*8);
#pragma unroll
        for (int c = 0; c < 4; c++)
            GLDS(Vb + (size_t)(c*32 + tid/8) * S_ + ks + (tid & 7)*8,   sVt + c*2048 + tid*8);
        __syncthreads();   // sK/sVt ready (shared across waves)

        // S = Q K^T; write to wave-private sS rows in plain [q][k]
        f32x4 sc[4] = {};
#pragma unroll
        for (int j = 0; j < 4; j++)
#pragma unroll
            for (int c = 0; c < 4; c++) {
                bf16x8 kf = *(const bf16x8*)&sK[(j*16 + lrow)*128 + c*32 + lk];
                sc[j] = __builtin_amdgcn_mfma_f32_16x16x32_bf16(qf[c], kf, sc[j], 0, 0, 0);
            }
#pragma unroll
        for (int j = 0; j < 4; j++) {
            const int kcol = j*16 + lrow;
#pragma unroll
            for (int r = 0; r < 4; r++) {
                const int qrow = wave*16 + quad*4 + r;
                float v = sc[j][r] * SCALE_;
                sS[qrow*65 + kcol] = (ks + kcol <= q0 + qrow) ? v : -1e30f;
            }
        }

        // parallel online softmax: lane (quad,lrow) -> row lrow, cols quad*16..+15
        {
            const int row = wave*16 + lrow;
            const float* Sr = &sS[row*65 + quad*16];
            float tm = -1e30f;
#pragma unroll
            for (int c = 0; c < 16; c++) tm = fmaxf(tm, Sr[c]);
            tm = fmaxf(tm, __shfl_xor(tm, 16, 64));
            tm = fmaxf(tm, __shfl_xor(tm, 32, 64));
            float mprev = sM[row];
            float mn = fmaxf(mprev, tm);
            float alpha = __expf(mprev - mn);
            float sum = 0.f;
            unsigned short* Pr = &sP[row*72 + quad*16];
#pragma unroll
            for (int c4 = 0; c4 < 4; c4++) {
                ushort4 o;
                float p0 = __expf(Sr[c4*4+0] - mn);
                float p1 = __expf(Sr[c4*4+1] - mn);
                float p2 = __expf(Sr[c4*4+2] - mn);
                float p3 = __expf(Sr[c4*4+3] - mn);
                sum += p0 + p1 + p2 + p3;
                o.x = f2bf(p0); o.y = f2bf(p1); o.z = f2bf(p2); o.w = f2bf(p3);
                *(ushort4*)&Pr[c4*4] = o;
            }
            sum += __shfl_xor(sum, 16, 64);
            sum += __shfl_xor(sum, 32, 64);
            if (quad == 0) {
                sM[row] = mn;
                sL[row] = sL[row]*alpha + sum;
                sAl[row] = alpha;
            }
        }

        // rescale O, then O += P V  (sP/sAl wave-private; wave-ordered LDS)
        float al[4];
#pragma unroll
        for (int r = 0; r < 4; r++) al[r] = sAl[wave*16 + quad*4 + r];
#pragma unroll
        for (int jo = 0; jo < 8; jo++)
#pragma unroll
            for (int r = 0; r < 4; r++) O[jo][r] *= al[r];
#pragma unroll
        for (int c = 0; c < 2; c++) {
            bf16x8 pf = *(const bf16x8*)&sP[(wave*16 + lrow)*72 + c*32 + lk];
#pragma unroll
            for (int jo = 0; jo < 8; jo++) {
                bf16x8 vf = *(const bf16x8*)&sVt[(jo*16 + lrow)*64 + c*32 + lk];
                O[jo] = __builtin_amdgcn_mfma_f32_16x16x32_bf16(pf, vf, O[jo], 0, 0, 0);
            }
        }
        __syncthreads();   // all waves done with sK/sVt before next GLDS
    }

    float li[4];
#pragma unroll
    for (int r = 0; r < 4; r++) li[r] = sL[wave*16 + quad*4 + r];
#pragma unroll
    for (int jo = 0; jo < 8; jo++) {
        const int dcol = jo*16 + lrow;
#pragma unroll
        for (int r = 0; r < 4; r++) {
            const int srow = q0 + wave*16 + quad*4 + r;
            ctx[((size_t)b * S_ + srow) * D_ + h*HD_ + dcol] = f2bf(O[jo][r] / li[r]);
        }
    }
}

// ---------------------------------------------------------------- launch
extern "C" void kernel_launch(void* const* d_in, const int* in_sizes, int n_in,
                              void* d_out, int out_size, void* d_ws, size_t ws_size,
                              hipStream_t stream) {
    const float* hs   = (const float*)d_in[0];
    // d_in[1] attention_mask: all ones, unused by the reference math
    const float* Wqkv = (const float*)d_in[2];
    const float* bqkv = (const float*)d_in[3];
    const float* Wd   = (const float*)d_in[4];
    const float* bd   = (const float*)d_in[5];
    float* out = (float*)d_out;

    char* ws  = (char*)d_ws;
    char* dob = (char*)d_out;
    // Memory map (base footprint 32 MiB, verified r4-r6):
    //   ws[0,16MiB):   Vt [bh][d][s]; WdT at ws[0,8MiB) after flash.
    //   ws[16,24MiB):  TW (per-chunk W^T) during gemm1; ctx ws[16,32) after.
    //   ws[32,48MiB):  Xbf (optional, only if ws_size >= 48MiB).
    //   d_out[0,16):   Qg ; d_out[16,32): Kg (dead before gemm2 writes).
    unsigned short* Vt  = (unsigned short*)(ws);
    unsigned short* WdT = (unsigned short*)(ws);
    unsigned short* TW  = (unsigned short*)(ws + 16777216);
    unsigned short* ctx = (unsigned short*)(ws + 16777216);
    unsigned short* Qg  = (unsigned short*)(dob);
    unsigned short* Kg  = (unsigned short*)(dob + 16777216);

    const bool have_xbf = (ws_size >= (size_t)50331648);
    unsigned short* Xbf = (unsigned short*)(ws + 33554432);

    // 1. QKV projection in 3 column-chunks: transpose chunk -> GEMM (+RoPE/split)
    if (have_xbf) {
        int n4 = M_ * D_ / 4;
        cast_bf16_kernel<<<dim3((n4 + 255) / 256), dim3(256), 0, stream>>>(hs, Xbf, n4);
        for (int c = 0; c < 3; c++) {
            transpose_cast_kernel<<<dim3(64, 64), dim3(256), 0, stream>>>(
                Wqkv + c*2048, TW, D_, N3_);
            gemm_bt2_kernel<1, 1><<<dim3(16, 32), dim3(256), 0, stream>>>(
                Xbf, TW, bqkv, Qg, Kg, Vt, N3_, D_, c*2048);
        }
    } else {
        for (int c = 0; c < 3; c++) {
            transpose_cast_kernel<<<dim3(64, 64), dim3(256), 0, stream>>>(
                Wqkv + c*2048, TW, D_, N3_);
            gemm_bt2_kernel<0, 1><<<dim3(16, 32), dim3(256), 0, stream>>>(
                hs, TW, bqkv, Qg, Kg, Vt, N3_, D_, c*2048);
        }
    }
    // 2. causal flash attention (parallel wave-private softmax)
    flash3_kernel<<<dim3(S_/64, B_*H_), dim3(256), 0, stream>>>(Qg, Kg, Vt, ctx);
    // 3. W_dense^T (Vt dead), then dense projection, fp32 out
    transpose_cast_kernel<<<dim3(64, 64), dim3(256), 0, stream>>>(
        Wd, WdT, D_, D_);
    gemm_bt2_kernel<1, 0><<<dim3(16, 32), dim3(256), 0, stream>>>(
        ctx, WdT, bd, out, nullptr, nullptr, D_, D_, 0);
}